// Round 5
// baseline (10905.293 us; speedup 1.0000x reference)
//
#include <hip/hip_runtime.h>
#include <hip/hip_fp16.h>
#include <cstdint>
#include <cstddef>

// Problem constants
#define B_   64
#define S_   512
#define F_   512
#define H_   1024
#define KTOT 1536
#define EPS_ 1e-3f
#define NBLK 128
#define NTHR 512
#define TBUF 32

typedef _Float16 f16x8 __attribute__((ext_vector_type(8)));
typedef float    f32x4 __attribute__((ext_vector_type(4)));
typedef unsigned u32x4 __attribute__((ext_vector_type(4)));

// workspace layout (bytes)
#define WS_HBUF_OFF 0                 // tagged h: u32[3][64][1024] = 768 KB
#define WS_WT_OFF   (1024*1024)       // fp16 [3*1024][1536] = 9 MB
// LDS layout (bytes)
#define LDS_XW      (96*1024)                 // x-part weights, swizzled
#define LDS_RED     (LDS_XW)                  // f32[3][512] = 6 KB
#define LDS_HLOG    (LDS_XW + 6*1024)         // fp16[TBUF][512] = 32 KB
#define LDS_BYTES   (LDS_XW + 6*1024 + TBUF*512*2)   // 137216

#define MFMA16(A,Bf,C) __builtin_amdgcn_mfma_f32_16x16x32_f16(A, Bf, C, 0, 0, 0)

// ---------------- weight prep: fp16, transposed, [3*H][KTOT] ----------------
// Wt[(g*H + j)][k] = (k < H) ? W_g[k][j] : U_g[k-H][j]
__global__ void prep_weights(const float* __restrict__ Wr, const float* __restrict__ Wc,
                             const float* __restrict__ Wo, const float* __restrict__ Ur,
                             const float* __restrict__ Uc, const float* __restrict__ Uo,
                             _Float16* __restrict__ Wt) {
    int b  = blockIdx.x;            // 0..191
    int g  = b >> 6;                // gate 0..2
    int j0 = (b & 63) << 4;         // 16 columns per block
    const float* W = (g == 0) ? Wr : (g == 1) ? Wc : Wo;
    const float* U = (g == 0) ? Ur : (g == 1) ? Uc : Uo;
    int jj = threadIdx.x & 15;
    int kk = threadIdx.x >> 4;      // 0..15
    for (int k0 = 0; k0 < KTOT; k0 += 16) {
        int k = k0 + kk;
        float v = (k < H_) ? W[(size_t)k * H_ + j0 + jj]
                           : U[(size_t)(k - H_) * H_ + j0 + jj];
        Wt[(size_t)(g * H_ + j0 + jj) * KTOT + k] = (_Float16)v;
    }
}

// ---------------- persistent tagged-h recurrence kernel ----------------
// 128 blocks x 512 threads (8 waves, 2/SIMD, 1 block/CU via LDS).
// Logical partition: group = bid>>5 (16 batch rows), cg = bid&31 (32 h-cols).
// Wave w K-split: h-k [128w,+128), x-k [64w,+64). M=16 fully used (no dup).
// h exchanged as {tag,fp16} u32 words -> ONE LLC round trip per step.
// out is buffered in LDS (fp16) and flushed every TBUF steps (no per-step
// HBM store-ack on the critical path). x and ts prefetched a full step ahead.
__global__ __launch_bounds__(NTHR, 2)
void plstm_tag(const float* __restrict__ x,
               const float* __restrict__ ts,
               const float* __restrict__ br,
               const float* __restrict__ bc,
               const float* __restrict__ bo,
               const _Float16* __restrict__ Wt,
               unsigned* __restrict__ hbuf,     // [3][64][1024] u32 tagged
               float* __restrict__ out) {
    extern __shared__ char lds[];
    float*    red  = (float*)(lds + LDS_RED);     // [3][512] f32
    _Float16* hlog = (_Float16*)(lds + LDS_HLOG); // [TBUF][512]

    const int tid = threadIdx.x;
    const int bid = blockIdx.x;
    const int grp = bid >> 5;            // batch-row group 0..3
    const int cg  = bid & 31;            // h-col group 0..31
    const int r0  = grp << 4;            // 16 rows
    const int c0  = cg << 5;             // 32 cols

    const int lane = tid & 63;
    const int w    = tid >> 6;           // wave 0..7
    const int arow = r0 + (lane & 15);   // A row (M=16, fully used)
    const int kblk = lane >> 4;          // 0..3
    const int jcol = lane & 15;          // B-fragment column within 16-col tile

    // ---- stage x-part weights into LDS (swizzled), zero red ----
    for (int m = tid; m < 96 * 64; m += NTHR) {
        const int R   = m >> 6;          // 0..95: (g3*2+ct)*16 + jcol
        const int kc  = m & 63;
        const int g3  = R >> 5;
        const int rem = R & 31;
        f16x8 v = *(const f16x8*)(Wt + (size_t)(g3 * H_ + c0 + rem) * KTOT + H_ + kc * 8);
        const int dst = (R * 1024 + kc * 16) ^ ((R & 7) << 4);
        *(f16x8*)(lds + dst) = v;
    }
    red[tid] = 0.f; red[512 + tid] = 0.f; red[1024 + tid] = 0.f;

    // ---- h-part weights to registers: 3 gates x 2 col-tiles x 4 subk ----
    f16x8 bf[3][2][4];
    #pragma unroll
    for (int g3 = 0; g3 < 3; ++g3)
        #pragma unroll
        for (int ct = 0; ct < 2; ++ct)
            #pragma unroll
            for (int sub = 0; sub < 4; ++sub)
                bf[g3][ct][sub] = *(const f16x8*)(Wt
                    + (size_t)(g3 * H_ + c0 + ct * 16 + jcol) * KTOT
                    + w * 128 + sub * 32 + kblk * 8);
    __syncthreads();

    const int erow = tid >> 5;           // elementwise: 16 rows x 32 cols = 512
    const int ecol = tid & 31;
    const int gb   = r0 + erow;
    const int gh   = c0 + ecol;
    const float biasr = br[gh], biasc = bc[gh], biaso = bo[gh];
    float cst = 0.f, kst = 0.f, hval = 0.f;

    // ---- prefetch x, ts for t=0; pre-issue tag batch for t=0 ----
    f32x4 xn0, xn1, xn2, xn3;
    {
        const float* xp = x + (size_t)arow * S_ * F_ + w * 64 + kblk * 8;
        asm volatile("global_load_dwordx4 %0, %1, off" : "=v"(xn0) : "v"(xp));
        asm volatile("global_load_dwordx4 %0, %1, off" : "=v"(xn1) : "v"(xp + 4));
        asm volatile("global_load_dwordx4 %0, %1, off" : "=v"(xn2) : "v"(xp + 32));
        asm volatile("global_load_dwordx4 %0, %1, off" : "=v"(xn3) : "v"(xp + 36));
    }
    float tvn = ts[(size_t)gb * S_];
    u32x4 q[8];
    {
        const unsigned* hb = hbuf + (size_t)arow * H_ + w * 128 + kblk * 8;  // slot 0
        #pragma unroll
        for (int s = 0; s < 4; ++s) {
            asm volatile("global_load_dwordx4 %0, %1, off sc0 sc1"
                         : "=v"(q[2 * s]) : "v"(hb + s * 32));
            asm volatile("global_load_dwordx4 %0, %1, off sc0 sc1"
                         : "=v"(q[2 * s + 1]) : "v"(hb + s * 32 + 4));
        }
    }

    for (int t = 0; t < S_; ++t) {
        const unsigned* hb = hbuf + (size_t)(t % 3) * B_ * H_
                                  + (size_t)arow * H_ + w * 128 + kblk * 8;
        // ---- poll: all 32 words must carry tag == t ----
        const unsigned tt = ((unsigned)t << 16) | (unsigned)t;
        for (unsigned it = 0; it < (1u << 13); ++it) {
            asm volatile("s_waitcnt vmcnt(0)" ::: "memory");
            __builtin_amdgcn_sched_barrier(0);
            unsigned bad = 0;
            #pragma unroll
            for (int i = 0; i < 8; ++i) {
                unsigned t0 = __builtin_amdgcn_perm(q[i][1], q[i][0], 0x07060302u);
                unsigned t1 = __builtin_amdgcn_perm(q[i][3], q[i][2], 0x07060302u);
                bad |= (t0 ^ tt) | (t1 ^ tt);
            }
            if (__all(bad == 0)) break;
            #pragma unroll
            for (int s = 0; s < 4; ++s) {
                asm volatile("global_load_dwordx4 %0, %1, off sc0 sc1"
                             : "=v"(q[2 * s]) : "v"(hb + s * 32));
                asm volatile("global_load_dwordx4 %0, %1, off sc0 sc1"
                             : "=v"(q[2 * s + 1]) : "v"(hb + s * 32 + 4));
            }
        }
        const float tv = tvn;

        // ---- strip tags -> h fragments ----
        f16x8 hfr[4];
        #pragma unroll
        for (int s = 0; s < 4; ++s) {
            union { u32x4 u; f16x8 f; } cv;
            cv.u[0] = __builtin_amdgcn_perm(q[2 * s][1],     q[2 * s][0],     0x05040100u);
            cv.u[1] = __builtin_amdgcn_perm(q[2 * s][3],     q[2 * s][2],     0x05040100u);
            cv.u[2] = __builtin_amdgcn_perm(q[2 * s + 1][1], q[2 * s + 1][0], 0x05040100u);
            cv.u[3] = __builtin_amdgcn_perm(q[2 * s + 1][3], q[2 * s + 1][2], 0x05040100u);
            hfr[s] = cv.f;
        }

        // ---- x fragments from prefetched regs ----
        f16x8 xf0, xf1;
        #pragma unroll
        for (int r = 0; r < 4; ++r) { xf0[r] = (_Float16)xn0[r]; xf0[4 + r] = (_Float16)xn1[r]; }
        #pragma unroll
        for (int r = 0; r < 4; ++r) { xf1[r] = (_Float16)xn2[r]; xf1[4 + r] = (_Float16)xn3[r]; }

        // ---- MFMAs: x-part (LDS weights) + h-part (reg weights) ----
        f32x4 acc[3][2] = {};
        #pragma unroll
        for (int g3 = 0; g3 < 3; ++g3) {
            const int sw = (jcol & 7) << 4;
            #pragma unroll
            for (int s = 0; s < 2; ++s) {
                const int koff = (w * 64 + s * 32 + kblk * 8) * 2;
                f16x8 w0 = *(const f16x8*)(lds + ((((g3 * 2 + 0) * 16 + jcol) * 1024 + koff) ^ sw));
                f16x8 w1 = *(const f16x8*)(lds + ((((g3 * 2 + 1) * 16 + jcol) * 1024 + koff) ^ sw));
                f16x8 xf = s ? xf1 : xf0;
                acc[g3][0] = MFMA16(xf, w0, acc[g3][0]);
                acc[g3][1] = MFMA16(xf, w1, acc[g3][1]);
            }
            #pragma unroll
            for (int s = 0; s < 4; ++s) {
                acc[g3][0] = MFMA16(hfr[s], bf[g3][0][s], acc[g3][0]);
                acc[g3][1] = MFMA16(hfr[s], bf[g3][1][s], acc[g3][1]);
            }
        }

        // ---- prefetch x, ts for t+1 (latency hidden by rest of step) ----
        {
            const int tn = (t + 1 < S_) ? t + 1 : t;
            const float* xp = x + ((size_t)arow * S_ + tn) * F_ + w * 64 + kblk * 8;
            asm volatile("global_load_dwordx4 %0, %1, off" : "=v"(xn0) : "v"(xp));
            asm volatile("global_load_dwordx4 %0, %1, off" : "=v"(xn1) : "v"(xp + 4));
            asm volatile("global_load_dwordx4 %0, %1, off" : "=v"(xn2) : "v"(xp + 32));
            asm volatile("global_load_dwordx4 %0, %1, off" : "=v"(xn3) : "v"(xp + 36));
            tvn = ts[(size_t)gb * S_ + tn];
        }

        // ---- cross-wave reduce via LDS float atomics ----
        {
            const int crow = (lane >> 4) << 2;
            const int ccol = lane & 15;
            #pragma unroll
            for (int g3 = 0; g3 < 3; ++g3)
                #pragma unroll
                for (int ct = 0; ct < 2; ++ct)
                    #pragma unroll
                    for (int i = 0; i < 4; ++i)
                        atomicAdd(&red[g3 * 512 + (crow + i) * 32 + ct * 16 + ccol],
                                  acc[g3][ct][i]);
        }
        __syncthreads();

        // ---- read partials; zero own slots for next step (same thread/addr) ----
        float pr = biasr + red[tid];
        float pc = biasc + red[512 + tid];
        float po = biaso + red[1024 + tid];
        red[tid] = 0.f; red[512 + tid] = 0.f; red[1024 + tid] = 0.f;

        // ---- elementwise pLSTM update (f32) ----
        const float r = 1.f / (1.f + __expf(-pr));
        kst = r * tv + (1.f - r) * kst;
        const float e2 = __expf(2.f * pc);
        const float ctil = (e2 - 1.f) / (e2 + 1.f);
        const float d = tv - kst;
        const float f = __fsqrt_rn((d + EPS_) / (d + 1.f));  // ((d+1)/(d+eps))^-0.5
        cst = f * cst + (1.f - f) * ctil;
        const float o = 1.f / (1.f + __expf(-po));
        const float e2c = __expf(2.f * cst);
        hval = o * ((e2c - 1.f) / (e2c + 1.f));

        // ---- publish tagged h for t+1 (single u32, one LLC hop) ----
        if (t + 1 < S_) {
            union { _Float16 hf; unsigned short us; } cv; cv.hf = (_Float16)hval;
            const unsigned word = ((unsigned)(t + 1) << 16) | (unsigned)cv.us;
            unsigned* hp = hbuf + (size_t)((t + 1) % 3) * B_ * H_ + (size_t)gb * H_ + gh;
            asm volatile("global_store_dword %0, %1, off sc0 sc1"
                         :: "v"(hp), "v"(word) : "memory");
        }

        // ---- log h to LDS; burst-flush every TBUF steps ----
        hlog[(t & (TBUF - 1)) * 512 + tid] = (_Float16)hval;
        if ((t & (TBUF - 1)) == TBUF - 1) {
            __syncthreads();   // hlog[last] visible to all
            const int t0 = t - (TBUF - 1);
            #pragma unroll
            for (int p = 0; p < 4; ++p) {
                const int m  = p * 512 + tid;     // 0..2047 chunks of 8 fp16
                const int tb = m >> 6;
                const int c  = m & 63;
                f16x8 v = *(const f16x8*)(hlog + tb * 512 + c * 8);
                float* op = out + ((size_t)(r0 + (c >> 2)) * S_ + t0 + tb) * H_
                                + c0 + (c & 3) * 8;
                f32x4 o0, o1;
                #pragma unroll
                for (int r2 = 0; r2 < 4; ++r2) { o0[r2] = (float)v[r2]; o1[r2] = (float)v[4 + r2]; }
                *(f32x4*)op = o0;
                *(f32x4*)(op + 4) = o1;
            }
        }

        // ---- pre-issue first tag batch for t+1 ----
        if (t + 1 < S_) {
            const unsigned* hn = hbuf + (size_t)((t + 1) % 3) * B_ * H_
                                      + (size_t)arow * H_ + w * 128 + kblk * 8;
            #pragma unroll
            for (int s = 0; s < 4; ++s) {
                asm volatile("global_load_dwordx4 %0, %1, off sc0 sc1"
                             : "=v"(q[2 * s]) : "v"(hn + s * 32));
                asm volatile("global_load_dwordx4 %0, %1, off sc0 sc1"
                             : "=v"(q[2 * s + 1]) : "v"(hn + s * 32 + 4));
            }
        }
    }

    // ---- final states (exact f32) ----
    const size_t BSH = (size_t)B_ * S_ * H_;
    out[BSH +                       (size_t)gb * H_ + gh] = hval;  // h_T
    out[BSH + (size_t)B_ * H_ +     (size_t)gb * H_ + gh] = cst;   // c_T
    out[BSH + 2 * (size_t)B_ * H_ + (size_t)gb * H_ + gh] = kst;   // k_T
}

extern "C" void kernel_launch(void* const* d_in, const int* in_sizes, int n_in,
                              void* d_out, int out_size, void* d_ws, size_t ws_size,
                              hipStream_t stream) {
    (void)in_sizes; (void)n_in; (void)out_size; (void)ws_size;
    const float* x  = (const float*)d_in[0];
    const float* ts = (const float*)d_in[1];
    const float* Ur = (const float*)d_in[2];
    const float* Wr = (const float*)d_in[3];
    const float* br = (const float*)d_in[4];
    const float* Uc = (const float*)d_in[5];
    const float* Wc = (const float*)d_in[6];
    const float* bc = (const float*)d_in[7];
    const float* Uo = (const float*)d_in[8];
    const float* Wo = (const float*)d_in[9];
    const float* bo = (const float*)d_in[10];
    float* out = (float*)d_out;

    char* ws = (char*)d_ws;
    unsigned*  hbuf = (unsigned*)(ws + WS_HBUF_OFF);
    _Float16*  Wt   = (_Float16*)(ws + WS_WT_OFF);

    // zero ALL 3 tagged-h slots every launch (stale tags from prior replay
    // would false-positive the exact-match poll). Slot 0 = {tag 0, h=0} ✓.
    hipMemsetAsync(hbuf, 0, 3 * B_ * H_ * 4, stream);

    prep_weights<<<192, 256, 0, stream>>>(Wr, Wc, Wo, Ur, Uc, Uo, Wt);

    hipFuncSetAttribute((const void*)plstm_tag,
                        hipFuncAttributeMaxDynamicSharedMemorySize, LDS_BYTES);
    plstm_tag<<<NBLK, NTHR, LDS_BYTES, stream>>>(x, ts, br, bc, bo, Wt, hbuf, out);
}

// Round 7
// 6994.094 us; speedup vs baseline: 1.5592x; 1.5592x over previous
//
#include <hip/hip_runtime.h>
#include <hip/hip_fp16.h>
#include <cstdint>
#include <cstddef>

// Problem constants
#define B_   64
#define S_   512
#define F_   512
#define H_   1024
#define KTOT 1536
#define EPS_ 1e-3f
#define NBLK 128
#define NTHR 512

typedef _Float16 f16x8 __attribute__((ext_vector_type(8)));
typedef float    f32x4 __attribute__((ext_vector_type(4)));
typedef unsigned u32x4 __attribute__((ext_vector_type(4)));

// workspace layout (bytes)
#define WS_HBUF_OFF 0                 // tagged h: u32[3][64][1024] = 768 KB
#define WS_WT_OFF   (1024*1024)       // fp16 [3*1024][1536] = 9 MB
// LDS layout (bytes): red f32[8][3][512] = 48 KB, hlog fp16[64][512] = 64 KB
#define LDS_RED     0
#define LDS_HLOG    (48*1024)
#define LDS_BYTES   (112*1024)

#define MFMA16(A,Bf,C) __builtin_amdgcn_mfma_f32_16x16x32_f16(A, Bf, C, 0, 0, 0)

// ---------------- weight prep: fp16, transposed, [3*H][KTOT] ----------------
// Wt[(g*H + j)][k] = (k < H) ? W_g[k][j] : U_g[k-H][j]
__global__ void prep_weights(const float* __restrict__ Wr, const float* __restrict__ Wc,
                             const float* __restrict__ Wo, const float* __restrict__ Ur,
                             const float* __restrict__ Uc, const float* __restrict__ Uo,
                             _Float16* __restrict__ Wt) {
    int b  = blockIdx.x;            // 0..191
    int g  = b >> 6;                // gate 0..2
    int j0 = (b & 63) << 4;         // 16 columns per block
    const float* W = (g == 0) ? Wr : (g == 1) ? Wc : Wo;
    const float* U = (g == 0) ? Ur : (g == 1) ? Uc : Uo;
    int jj = threadIdx.x & 15;
    int kk = threadIdx.x >> 4;      // 0..15
    for (int k0 = 0; k0 < KTOT; k0 += 16) {
        int k = k0 + kk;
        float v = (k < H_) ? W[(size_t)k * H_ + j0 + jj]
                           : U[(size_t)(k - H_) * H_ + j0 + jj];
        Wt[(size_t)(g * H_ + j0 + jj) * KTOT + k] = (_Float16)v;
    }
}

// ---------------- persistent tagged-h recurrence kernel ----------------
// 128 blocks x 512 threads (8 waves, 1 block/CU via 112KB LDS).
// Partition: group = bid>>5 (16 batch rows), cg = bid&31 (32 h-cols). M=16
// fully used. Wave w K-split: h-k [128w,+128), x-k [64w,+64). ALL weights in
// registers (144 VGPR/thread). h exchanged as {tag,fp16} u32 words (one LLC
// round trip). out buffered in a 64-deep LDS log, burst-flushed every 32
// steps (no per-step HBM store in the drain path). x/ts prefetched a full
// step ahead; x-part MFMAs execute during the tag-load flight.
//
// vmcnt LEDGER (counted waits — derive, don't guess):
//   priming: issue x(4), ts(1), tags(8) = 13 outstanding.
//            vmcnt(8) retires 13-8=5 oldest = x+ts. tags stay in flight.
//   loop tail (non-flush): x(4)+ts(1)+publish(1)+tags(8) = 14.
//            vmcnt(9) retires 5 = x+ts. publish+tags stay.
//   loop tail (flush step): +8 flush stores = 22.
//            vmcnt(9) retires 13 = x+ts+flush. publish+tags stay.
__global__ __launch_bounds__(NTHR, 2)
void plstm_reg(const float* __restrict__ x,
               const float* __restrict__ ts,
               const float* __restrict__ br,
               const float* __restrict__ bc,
               const float* __restrict__ bo,
               const _Float16* __restrict__ Wt,
               unsigned* __restrict__ hbuf,     // [3][64][1024] u32 tagged
               float* __restrict__ out) {
    extern __shared__ char lds[];
    float*    red  = (float*)(lds + LDS_RED);     // [8 waves][3 gates][512]
    _Float16* hlog = (_Float16*)(lds + LDS_HLOG); // [64][512]

    const int tid = threadIdx.x;
    const int bid = blockIdx.x;
    const int grp = bid >> 5;            // batch-row group 0..3
    const int cg  = bid & 31;            // h-col group 0..31
    const int r0  = grp << 4;            // 16 rows
    const int c0  = cg << 5;             // 32 cols

    const int lane = tid & 63;
    const int w    = tid >> 6;           // wave 0..7
    const int arow = r0 + (lane & 15);   // A row (M=16, fully used)
    const int kblk = lane >> 4;          // 0..3
    const int jcol = lane & 15;          // B-fragment column within 16-col tile

    // ---- ALL weights into registers ----
    // h-part: 3 gates x 2 col-tiles x 4 subk (k = w*128 + sub*32 + kblk*8)
    // x-part: 3 gates x 2 col-tiles x 2 subk (k = H + w*64 + sub*32 + kblk*8)
    f16x8 bfh[3][2][4], bfx[3][2][2];
    #pragma unroll
    for (int g3 = 0; g3 < 3; ++g3)
        #pragma unroll
        for (int ct = 0; ct < 2; ++ct) {
            const _Float16* base = Wt + (size_t)(g3 * H_ + c0 + ct * 16 + jcol) * KTOT;
            #pragma unroll
            for (int sub = 0; sub < 4; ++sub)
                bfh[g3][ct][sub] = *(const f16x8*)(base + w * 128 + sub * 32 + kblk * 8);
            #pragma unroll
            for (int sub = 0; sub < 2; ++sub)
                bfx[g3][ct][sub] = *(const f16x8*)(base + H_ + w * 64 + sub * 32 + kblk * 8);
        }

    const int erow = tid >> 5;           // elementwise: 16 rows x 32 cols = 512
    const int ecol = tid & 31;
    const int gb   = r0 + erow;
    const int gh   = c0 + ecol;
    const float biasr = br[gh], biasc = bc[gh], biaso = bo[gh];
    float cst = 0.f, kst = 0.f, hval = 0.f;

    // ---- priming: x(0), ts(0), tags(0); vmcnt(8) leaves ONLY tags in flight ----
    f32x4 xn0, xn1, xn2, xn3; float tvn;
    u32x4 q[8];
    {
        const float* xp = x + (size_t)arow * S_ * F_ + w * 64 + kblk * 8;
        asm volatile("global_load_dwordx4 %0, %1, off" : "=v"(xn0) : "v"(xp));
        asm volatile("global_load_dwordx4 %0, %1, off" : "=v"(xn1) : "v"(xp + 4));
        asm volatile("global_load_dwordx4 %0, %1, off" : "=v"(xn2) : "v"(xp + 32));
        asm volatile("global_load_dwordx4 %0, %1, off" : "=v"(xn3) : "v"(xp + 36));
        const float* tp = ts + (size_t)gb * S_;
        asm volatile("global_load_dword %0, %1, off" : "=v"(tvn) : "v"(tp));
        const unsigned* hb = hbuf + (size_t)arow * H_ + w * 128 + kblk * 8;  // slot 0
        #pragma unroll
        for (int s = 0; s < 4; ++s) {
            asm volatile("global_load_dwordx4 %0, %1, off sc0 sc1"
                         : "=v"(q[2 * s]) : "v"(hb + s * 32));
            asm volatile("global_load_dwordx4 %0, %1, off sc0 sc1"
                         : "=v"(q[2 * s + 1]) : "v"(hb + s * 32 + 4));
        }
    }
    asm volatile("s_waitcnt vmcnt(8)" ::: "memory");   // 13-8=5 retired: x + ts
    __builtin_amdgcn_sched_barrier(0);
    f16x8 xf0, xf1;
    #pragma unroll
    for (int r = 0; r < 4; ++r) { xf0[r] = (_Float16)xn0[r]; xf0[4 + r] = (_Float16)xn1[r]; }
    #pragma unroll
    for (int r = 0; r < 4; ++r) { xf1[r] = (_Float16)xn2[r]; xf1[4 + r] = (_Float16)xn3[r]; }
    float tv = tvn;

    for (int t = 0; t < S_; ++t) {
        // ---- x-part MFMAs (pure reg) overlap the tag-load flight ----
        f32x4 acc[3][2] = {};
        #pragma unroll
        for (int g3 = 0; g3 < 3; ++g3)
            #pragma unroll
            for (int ct = 0; ct < 2; ++ct) {
                acc[g3][ct] = MFMA16(xf0, bfx[g3][ct][0], acc[g3][ct]);
                acc[g3][ct] = MFMA16(xf1, bfx[g3][ct][1], acc[g3][ct]);
            }

        // ---- poll: all 32 tag-words must equal t ----
        const unsigned* hb = hbuf + (size_t)(t % 3) * B_ * H_
                                  + (size_t)arow * H_ + w * 128 + kblk * 8;
        const unsigned tt = ((unsigned)t << 16) | (unsigned)t;
        for (unsigned it = 0; it < (1u << 13); ++it) {
            asm volatile("s_waitcnt vmcnt(0)" ::: "memory");
            __builtin_amdgcn_sched_barrier(0);
            unsigned bad = 0;
            #pragma unroll
            for (int i = 0; i < 8; ++i) {
                unsigned t0 = __builtin_amdgcn_perm(q[i][1], q[i][0], 0x07060302u);
                unsigned t1 = __builtin_amdgcn_perm(q[i][3], q[i][2], 0x07060302u);
                bad |= (t0 ^ tt) | (t1 ^ tt);
            }
            if (__all(bad == 0)) break;
            #pragma unroll
            for (int s = 0; s < 4; ++s) {
                asm volatile("global_load_dwordx4 %0, %1, off sc0 sc1"
                             : "=v"(q[2 * s]) : "v"(hb + s * 32));
                asm volatile("global_load_dwordx4 %0, %1, off sc0 sc1"
                             : "=v"(q[2 * s + 1]) : "v"(hb + s * 32 + 4));
            }
        }

        // ---- strip tags -> h fragments; h-part MFMAs (pure reg) ----
        f16x8 hfr[4];
        #pragma unroll
        for (int s = 0; s < 4; ++s) {
            union { u32x4 u; f16x8 f; } cv;
            cv.u[0] = __builtin_amdgcn_perm(q[2 * s][1],     q[2 * s][0],     0x05040100u);
            cv.u[1] = __builtin_amdgcn_perm(q[2 * s][3],     q[2 * s][2],     0x05040100u);
            cv.u[2] = __builtin_amdgcn_perm(q[2 * s + 1][1], q[2 * s + 1][0], 0x05040100u);
            cv.u[3] = __builtin_amdgcn_perm(q[2 * s + 1][3], q[2 * s + 1][2], 0x05040100u);
            hfr[s] = cv.f;
        }
        #pragma unroll
        for (int s = 0; s < 4; ++s)
            #pragma unroll
            for (int g3 = 0; g3 < 3; ++g3) {
                acc[g3][0] = MFMA16(hfr[s], bfh[g3][0][s], acc[g3][0]);
                acc[g3][1] = MFMA16(hfr[s], bfh[g3][1][s], acc[g3][1]);
            }

        // ---- prefetch x, ts for t+1 (after poll so retries never drain them) ----
        if (t + 1 < S_) {
            const float* xp = x + ((size_t)arow * S_ + (t + 1)) * F_ + w * 64 + kblk * 8;
            asm volatile("global_load_dwordx4 %0, %1, off" : "=v"(xn0) : "v"(xp));
            asm volatile("global_load_dwordx4 %0, %1, off" : "=v"(xn1) : "v"(xp + 4));
            asm volatile("global_load_dwordx4 %0, %1, off" : "=v"(xn2) : "v"(xp + 32));
            asm volatile("global_load_dwordx4 %0, %1, off" : "=v"(xn3) : "v"(xp + 36));
            const float* tp = ts + (size_t)gb * S_ + (t + 1);
            asm volatile("global_load_dword %0, %1, off" : "=v"(tvn) : "v"(tp));
        }

        // ---- cross-wave reduce: explicit per-wave slots (NO atomics) ----
        {
            float* rw = red + w * 1536;
            const int crow = (lane >> 4) << 2;     // C row base
            const int ccol = lane & 15;
            #pragma unroll
            for (int i = 0; i < 4; ++i) {
                const int rr = (crow + i) * 32 + ccol;
                rw[rr]              = acc[0][0][i];  rw[rr + 16]        = acc[0][1][i];
                rw[512 + rr]        = acc[1][0][i];  rw[512 + rr + 16]  = acc[1][1][i];
                rw[1024 + rr]       = acc[2][0][i];  rw[1024 + rr + 16] = acc[2][1][i];
            }
        }
        __syncthreads();

        // ---- burst-flush h-log every 32 steps (64-deep buffer: no 2nd barrier) ----
        if ((t & 31) == 0 && t) {
            const int tbase = t - 32;
            #pragma unroll
            for (int p = 0; p < 4; ++p) {
                const int m  = p * 512 + tid;
                const int dt = m >> 6;               // 0..31
                const int c  = m & 63;
                f16x8 v = *(const f16x8*)(hlog + ((tbase + dt) & 63) * 512 + c * 8);
                float* op = out + ((size_t)(r0 + (c >> 2)) * S_ + tbase + dt) * H_
                                + c0 + (c & 3) * 8;
                f32x4 o0, o1;
                #pragma unroll
                for (int r2 = 0; r2 < 4; ++r2) { o0[r2] = (float)v[r2]; o1[r2] = (float)v[4 + r2]; }
                *(f32x4*)op = o0;
                *(f32x4*)(op + 4) = o1;
            }
        }

        // ---- sum partials + elementwise pLSTM update (f32) ----
        float pr = biasr, pc = biasc, po = biaso;
        #pragma unroll
        for (int ww = 0; ww < 8; ++ww) {
            pr += red[ww * 1536 + tid];
            pc += red[ww * 1536 + 512 + tid];
            po += red[ww * 1536 + 1024 + tid];
        }
        const float r = 1.f / (1.f + __expf(-pr));
        kst = r * tv + (1.f - r) * kst;
        const float e2 = __expf(2.f * pc);
        const float ctil = (e2 - 1.f) / (e2 + 1.f);
        const float d = tv - kst;
        const float f = __fsqrt_rn((d + EPS_) / (d + 1.f));  // ((d+1)/(d+eps))^-0.5
        cst = f * cst + (1.f - f) * ctil;
        const float o = 1.f / (1.f + __expf(-po));
        const float e2c = __expf(2.f * cst);
        hval = o * ((e2c - 1.f) / (e2c + 1.f));

        hlog[(t & 63) * 512 + tid] = (_Float16)hval;

        if (t + 1 < S_) {
            // publish tagged h (one u32, LLC), pre-issue tags(t+1)
            union { _Float16 hf; unsigned short us; } cv; cv.hf = (_Float16)hval;
            const unsigned word = ((unsigned)(t + 1) << 16) | (unsigned)cv.us;
            unsigned* hp = hbuf + (size_t)((t + 1) % 3) * B_ * H_ + (size_t)gb * H_ + gh;
            asm volatile("global_store_dword %0, %1, off sc0 sc1"
                         :: "v"(hp), "v"(word) : "memory");
            const unsigned* hn = hbuf + (size_t)((t + 1) % 3) * B_ * H_
                                      + (size_t)arow * H_ + w * 128 + kblk * 8;
            #pragma unroll
            for (int s = 0; s < 4; ++s) {
                asm volatile("global_load_dwordx4 %0, %1, off sc0 sc1"
                             : "=v"(q[2 * s]) : "v"(hn + s * 32));
                asm volatile("global_load_dwordx4 %0, %1, off sc0 sc1"
                             : "=v"(q[2 * s + 1]) : "v"(hn + s * 32 + 4));
            }
            // tail: retire x+ts (+any flush stores); leave publish+tags in flight
            asm volatile("s_waitcnt vmcnt(9)" ::: "memory");
            __builtin_amdgcn_sched_barrier(0);
            #pragma unroll
            for (int r2 = 0; r2 < 4; ++r2) { xf0[r2] = (_Float16)xn0[r2]; xf0[4 + r2] = (_Float16)xn1[r2]; }
            #pragma unroll
            for (int r2 = 0; r2 < 4; ++r2) { xf1[r2] = (_Float16)xn2[r2]; xf1[4 + r2] = (_Float16)xn3[r2]; }
            tv = tvn;
        }
    }

    // ---- final flush of last 32 steps + final states ----
    __syncthreads();
    {
        const int tbase = S_ - 32;
        #pragma unroll
        for (int p = 0; p < 4; ++p) {
            const int m  = p * 512 + tid;
            const int dt = m >> 6;
            const int c  = m & 63;
            f16x8 v = *(const f16x8*)(hlog + ((tbase + dt) & 63) * 512 + c * 8);
            float* op = out + ((size_t)(r0 + (c >> 2)) * S_ + tbase + dt) * H_
                            + c0 + (c & 3) * 8;
            f32x4 o0, o1;
            #pragma unroll
            for (int r2 = 0; r2 < 4; ++r2) { o0[r2] = (float)v[r2]; o1[r2] = (float)v[4 + r2]; }
            *(f32x4*)op = o0;
            *(f32x4*)(op + 4) = o1;
        }
    }
    const size_t BSH = (size_t)B_ * S_ * H_;
    out[BSH +                       (size_t)gb * H_ + gh] = hval;  // h_T
    out[BSH + (size_t)B_ * H_ +     (size_t)gb * H_ + gh] = cst;   // c_T
    out[BSH + 2 * (size_t)B_ * H_ + (size_t)gb * H_ + gh] = kst;   // k_T
}

extern "C" void kernel_launch(void* const* d_in, const int* in_sizes, int n_in,
                              void* d_out, int out_size, void* d_ws, size_t ws_size,
                              hipStream_t stream) {
    (void)in_sizes; (void)n_in; (void)out_size; (void)ws_size;
    const float* x  = (const float*)d_in[0];
    const float* ts = (const float*)d_in[1];
    const float* Ur = (const float*)d_in[2];
    const float* Wr = (const float*)d_in[3];
    const float* br = (const float*)d_in[4];
    const float* Uc = (const float*)d_in[5];
    const float* Wc = (const float*)d_in[6];
    const float* bc = (const float*)d_in[7];
    const float* Uo = (const float*)d_in[8];
    const float* Wo = (const float*)d_in[9];
    const float* bo = (const float*)d_in[10];
    float* out = (float*)d_out;

    char* ws = (char*)d_ws;
    unsigned*  hbuf = (unsigned*)(ws + WS_HBUF_OFF);
    _Float16*  Wt   = (_Float16*)(ws + WS_WT_OFF);

    // zero ALL 3 tagged-h slots every launch (stale tags from prior replay
    // would false-positive the exact-match poll). Slot 0 = {tag 0, h=0} ✓.
    hipMemsetAsync(hbuf, 0, 3 * B_ * H_ * 4, stream);

    prep_weights<<<192, 256, 0, stream>>>(Wr, Wc, Wo, Ur, Uc, Uo, Wt);

    hipFuncSetAttribute((const void*)plstm_reg,
                        hipFuncAttributeMaxDynamicSharedMemorySize, LDS_BYTES);
    plstm_reg<<<NBLK, NTHR, LDS_BYTES, stream>>>(x, ts, br, bc, bo, Wt, hbuf, out);
}

// Round 8
// 3687.127 us; speedup vs baseline: 2.9577x; 1.8969x over previous
//
#include <hip/hip_runtime.h>
#include <hip/hip_fp16.h>
#include <cstdint>
#include <cstddef>

// Problem constants
#define B_   64
#define S_   512
#define F_   512
#define H_   1024
#define KTOT 1536
#define EPS_ 1e-3f
#define NBLK 256
#define NTHR 512

typedef _Float16 f16x8 __attribute__((ext_vector_type(8)));
typedef float    f32x4 __attribute__((ext_vector_type(4)));
typedef unsigned u32x4 __attribute__((ext_vector_type(4)));

// workspace layout (bytes)
#define WS_HBUF_OFF 0                 // tagged h: u32[3][64][1024] = 768 KB
#define WS_WT_OFF   (1024*1024)       // fp16 [3*1024][1536] = 9 MB

#define MFMA16(A,Bf,C) __builtin_amdgcn_mfma_f32_16x16x32_f16(A, Bf, C, 0, 0, 0)

// ---------------- weight prep: fp16, transposed, [3*H][KTOT] ----------------
// Wt[(g*H + j)][k] = (k < H) ? W_g[k][j] : U_g[k-H][j]
__global__ void prep_weights(const float* __restrict__ Wr, const float* __restrict__ Wc,
                             const float* __restrict__ Wo, const float* __restrict__ Ur,
                             const float* __restrict__ Uc, const float* __restrict__ Uo,
                             _Float16* __restrict__ Wt) {
    int b  = blockIdx.x;            // 0..191
    int g  = b >> 6;                // gate 0..2
    int j0 = (b & 63) << 4;         // 16 columns per block
    const float* W = (g == 0) ? Wr : (g == 1) ? Wc : Wo;
    const float* U = (g == 0) ? Ur : (g == 1) ? Uc : Uo;
    int jj = threadIdx.x & 15;
    int kk = threadIdx.x >> 4;      // 0..15
    for (int k0 = 0; k0 < KTOT; k0 += 16) {
        int k = k0 + kk;
        float v = (k < H_) ? W[(size_t)k * H_ + j0 + jj]
                           : U[(size_t)(k - H_) * H_ + j0 + jj];
        Wt[(size_t)(g * H_ + j0 + jj) * KTOT + k] = (_Float16)v;
    }
}

// ---------------- persistent tagged-h recurrence kernel ----------------
// 256 blocks x 512 threads (8 waves). Partition (R4-proven dynamics):
// group = bid>>5 (8 batch rows), cg = bid&31 (32 h-cols). M=8 of 16 (lanes
// 8-15 duplicate rows — harmless, coalesced). Wave w K-split: h-k [128w,+128),
// x-k [64w,+64). Weights resident in AGPR/VGPR (144 regs). h exchanged as
// {tag,fp16} u32 words (tear-free; ONE LLC round trip). out buffered in a
// 64-deep LDS log, burst-flushed every 32 steps. x/ts prefetched a full step
// ahead; x-part MFMAs execute during the tag-load flight. Poll has s_sleep
// backoff + 2^17 cap (cascade-proof).
//
// vmcnt LEDGERS (counted waits — derived, not guessed):
//   priming  owners(w<4):   x4 + ts1 + tags8 = 13 -> vmcnt(8) retires 5 (x,ts)
//   priming  non-owners:    x4 +       tags8 = 12 -> vmcnt(8) retires 4 (x)
//   tail owners, non-flush: x4+ts1+pub1+tags8 = 14 -> vmcnt(9) retires 5 (x,ts)
//   tail owners, flush:     +4 flush stores  = 18 -> vmcnt(9) retires 9 (x,ts,flush)
//   tail non-own, non-flush: x4+tags8        = 12 -> vmcnt(8) retires 4 (x)
//   tail non-own, flush:    x4+flush4+tags8  = 16 -> vmcnt(8) retires 8 (x,flush)
__global__ __launch_bounds__(NTHR, 2)
void plstm_reg(const float* __restrict__ x,
               const float* __restrict__ ts,
               const float* __restrict__ br,
               const float* __restrict__ bc,
               const float* __restrict__ bo,
               const _Float16* __restrict__ Wt,
               unsigned* __restrict__ hbuf,     // [3][64][1024] u32 tagged
               float* __restrict__ out) {
    __shared__ float    red[8 * 768];       // [wave][gate][8*32] = 24 KB
    __shared__ _Float16 hlog[64 * 256];     // 64-deep h log      = 32 KB

    const int tid = threadIdx.x;
    const int bid = blockIdx.x;
    const int grp = bid >> 5;            // batch-row group 0..7
    const int cg  = bid & 31;            // h-col group 0..31
    const int r0  = grp << 3;            // 8 rows
    const int c0  = cg << 5;             // 32 cols

    const int lane = tid & 63;
    const int w    = tid >> 6;           // wave 0..7
    const int arow = r0 + (lane & 7);    // A rows (M=8; lanes 8-15 duplicate)
    const int kblk = lane >> 4;          // 0..3
    const int jcol = lane & 15;          // B-fragment column within 16-col tile
    const bool ownerw = (w < 4);         // waves 0-3 = owner threads (tid<256)

    // ---- ALL weights into registers (AGPR-resident on gfx950) ----
    f16x8 bfh[3][2][4], bfx[3][2][2];
    #pragma unroll
    for (int g3 = 0; g3 < 3; ++g3)
        #pragma unroll
        for (int ct = 0; ct < 2; ++ct) {
            const _Float16* base = Wt + (size_t)(g3 * H_ + c0 + ct * 16 + jcol) * KTOT;
            #pragma unroll
            for (int sub = 0; sub < 4; ++sub)
                bfh[g3][ct][sub] = *(const f16x8*)(base + w * 128 + sub * 32 + kblk * 8);
            #pragma unroll
            for (int sub = 0; sub < 2; ++sub)
                bfx[g3][ct][sub] = *(const f16x8*)(base + H_ + w * 64 + sub * 32 + kblk * 8);
        }

    const int erow = tid >> 5;           // owner mapping (tid<256): 8 rows x 32 cols
    const int ecol = tid & 31;
    const int gb   = r0 + (erow & 7);
    const int gh   = c0 + ecol;
    float biasr = 0.f, biasc = 0.f, biaso = 0.f;
    if (tid < 256) { biasr = br[gh]; biasc = bc[gh]; biaso = bo[gh]; }
    float cst = 0.f, kst = 0.f, hval = 0.f;

    // ---- drain compiler-issued loads so the counted ledger starts at 0 ----
    asm volatile("s_waitcnt vmcnt(0)" ::: "memory");
    __builtin_amdgcn_sched_barrier(0);

    // ---- priming: x(0), ts(0, owners), tags(0); vmcnt(8) leaves tags in flight ----
    f32x4 xn0, xn1, xn2, xn3; float tvn = 0.f;
    u32x4 q[8];
    {
        const float* xp = x + (size_t)arow * S_ * F_ + w * 64 + kblk * 8;
        asm volatile("global_load_dwordx4 %0, %1, off" : "=v"(xn0) : "v"(xp));
        asm volatile("global_load_dwordx4 %0, %1, off" : "=v"(xn1) : "v"(xp + 4));
        asm volatile("global_load_dwordx4 %0, %1, off" : "=v"(xn2) : "v"(xp + 32));
        asm volatile("global_load_dwordx4 %0, %1, off" : "=v"(xn3) : "v"(xp + 36));
        if (ownerw) {
            const float* tp = ts + (size_t)gb * S_;
            asm volatile("global_load_dword %0, %1, off" : "=v"(tvn) : "v"(tp));
        }
        const unsigned* hb = hbuf + (size_t)arow * H_ + w * 128 + kblk * 8;  // slot 0
        #pragma unroll
        for (int s = 0; s < 4; ++s) {
            asm volatile("global_load_dwordx4 %0, %1, off sc0 sc1"
                         : "=v"(q[2 * s]) : "v"(hb + s * 32));
            asm volatile("global_load_dwordx4 %0, %1, off sc0 sc1"
                         : "=v"(q[2 * s + 1]) : "v"(hb + s * 32 + 4));
        }
    }
    asm volatile("s_waitcnt vmcnt(8)" ::: "memory");
    __builtin_amdgcn_sched_barrier(0);
    f16x8 xf0, xf1;
    #pragma unroll
    for (int r = 0; r < 4; ++r) { xf0[r] = (_Float16)xn0[r]; xf0[4 + r] = (_Float16)xn1[r]; }
    #pragma unroll
    for (int r = 0; r < 4; ++r) { xf1[r] = (_Float16)xn2[r]; xf1[4 + r] = (_Float16)xn3[r]; }
    float tv = tvn;

    for (int t = 0; t < S_; ++t) {
        // ---- x-part MFMAs (pure reg) overlap the tag-load flight ----
        f32x4 acc[3][2] = {};
        #pragma unroll
        for (int g3 = 0; g3 < 3; ++g3)
            #pragma unroll
            for (int ct = 0; ct < 2; ++ct) {
                acc[g3][ct] = MFMA16(xf0, bfx[g3][ct][0], acc[g3][ct]);
                acc[g3][ct] = MFMA16(xf1, bfx[g3][ct][1], acc[g3][ct]);
            }

        // ---- poll: all 32 tag-words must equal t (backoff + big cap) ----
        const unsigned* hb = hbuf + (size_t)(t % 3) * B_ * H_
                                  + (size_t)arow * H_ + w * 128 + kblk * 8;
        const unsigned tt = ((unsigned)t << 16) | (unsigned)t;
        for (unsigned it = 0;;) {
            asm volatile("s_waitcnt vmcnt(0)" ::: "memory");
            __builtin_amdgcn_sched_barrier(0);
            unsigned bad = 0;
            #pragma unroll
            for (int i = 0; i < 8; ++i) {
                unsigned t0 = __builtin_amdgcn_perm(q[i][1], q[i][0], 0x07060302u);
                unsigned t1 = __builtin_amdgcn_perm(q[i][3], q[i][2], 0x07060302u);
                bad |= (t0 ^ tt) | (t1 ^ tt);
            }
            if (__all(bad == 0)) break;
            if (++it > (1u << 17)) break;              // cascade-proof cap
            if (it > 6) __builtin_amdgcn_s_sleep(2);   // decongest the LLC
            #pragma unroll
            for (int s = 0; s < 4; ++s) {
                asm volatile("global_load_dwordx4 %0, %1, off sc0 sc1"
                             : "=v"(q[2 * s]) : "v"(hb + s * 32));
                asm volatile("global_load_dwordx4 %0, %1, off sc0 sc1"
                             : "=v"(q[2 * s + 1]) : "v"(hb + s * 32 + 4));
            }
        }

        // ---- strip tags -> h fragments ----
        f16x8 hfr[4];
        #pragma unroll
        for (int s = 0; s < 4; ++s) {
            union { u32x4 u; f16x8 f; } cv;
            cv.u[0] = __builtin_amdgcn_perm(q[2 * s][1],     q[2 * s][0],     0x05040100u);
            cv.u[1] = __builtin_amdgcn_perm(q[2 * s][3],     q[2 * s][2],     0x05040100u);
            cv.u[2] = __builtin_amdgcn_perm(q[2 * s + 1][1], q[2 * s + 1][0], 0x05040100u);
            cv.u[3] = __builtin_amdgcn_perm(q[2 * s + 1][3], q[2 * s + 1][2], 0x05040100u);
            hfr[s] = cv.f;
        }

        // ---- prefetch x, ts for t+1 now (hidden under h-MFMA..elementwise) ----
        if (t + 1 < S_) {
            const float* xp = x + ((size_t)arow * S_ + (t + 1)) * F_ + w * 64 + kblk * 8;
            asm volatile("global_load_dwordx4 %0, %1, off" : "=v"(xn0) : "v"(xp));
            asm volatile("global_load_dwordx4 %0, %1, off" : "=v"(xn1) : "v"(xp + 4));
            asm volatile("global_load_dwordx4 %0, %1, off" : "=v"(xn2) : "v"(xp + 32));
            asm volatile("global_load_dwordx4 %0, %1, off" : "=v"(xn3) : "v"(xp + 36));
            if (ownerw) {
                const float* tp = ts + (size_t)gb * S_ + (t + 1);
                asm volatile("global_load_dword %0, %1, off" : "=v"(tvn) : "v"(tp));
            }
        }

        // ---- h-part MFMAs (pure reg) ----
        #pragma unroll
        for (int s = 0; s < 4; ++s)
            #pragma unroll
            for (int g3 = 0; g3 < 3; ++g3) {
                acc[g3][0] = MFMA16(hfr[s], bfh[g3][0][s], acc[g3][0]);
                acc[g3][1] = MFMA16(hfr[s], bfh[g3][1][s], acc[g3][1]);
            }

        // ---- cross-wave reduce: explicit per-wave slots (C rows 0-7 in lanes 0-31) ----
        if (lane < 32) {
            float* rw = red + w * 768;
            const int crow = (lane >> 4) << 2;
            const int ccol = lane & 15;
            #pragma unroll
            for (int i = 0; i < 4; ++i) {
                const int rr = (crow + i) * 32 + ccol;
                rw[rr]              = acc[0][0][i];  rw[rr + 16]         = acc[0][1][i];
                rw[256 + rr]        = acc[1][0][i];  rw[256 + rr + 16]   = acc[1][1][i];
                rw[512 + rr]        = acc[2][0][i];  rw[512 + rr + 16]   = acc[2][1][i];
            }
        }
        __syncthreads();   // barrier #1: red ready

        // ---- burst-flush h-log every 32 steps (asm stores, in the ledger) ----
        if ((t & 31) == 0 && t) {
            const int tbase = t - 32;
            #pragma unroll
            for (int p = 0; p < 2; ++p) {
                const int m  = p * 512 + tid;        // 0..1023 chunks of 8 fp16
                const int dt = m >> 5;               // 0..31
                const int c  = m & 31;               // chunk within step
                f16x8 v = *(const f16x8*)(hlog + ((tbase + dt) & 63) * 256 + c * 8);
                float* op = out + ((size_t)(r0 + (c >> 2)) * S_ + tbase + dt) * H_
                                + c0 + (c & 3) * 8;
                f32x4 o0, o1;
                #pragma unroll
                for (int r2 = 0; r2 < 4; ++r2) { o0[r2] = (float)v[r2]; o1[r2] = (float)v[4 + r2]; }
                asm volatile("global_store_dwordx4 %0, %1, off" :: "v"(op), "v"(o0) : "memory");
                asm volatile("global_store_dwordx4 %0, %1, off" :: "v"(op + 4), "v"(o1) : "memory");
            }
        }

        // ---- owners: sum partials (read red) ----
        float pr = biasr, pc = biasc, po = biaso;
        if (tid < 256) {
            #pragma unroll
            for (int ww = 0; ww < 8; ++ww) {
                pr += red[ww * 768 + tid];
                pc += red[ww * 768 + 256 + tid];
                po += red[ww * 768 + 512 + tid];
            }
        }
        __syncthreads();   // barrier #2: red free for next step's reduce-write

        if (tid < 256) {
            // ---- elementwise pLSTM update (f32) ----
            const float r = 1.f / (1.f + __expf(-pr));
            kst = r * tv + (1.f - r) * kst;
            const float e2 = __expf(2.f * pc);
            const float ctil = (e2 - 1.f) / (e2 + 1.f);
            const float d = tv - kst;
            const float f = __fsqrt_rn((d + EPS_) / (d + 1.f));  // ((d+1)/(d+eps))^-0.5
            cst = f * cst + (1.f - f) * ctil;
            const float o = 1.f / (1.f + __expf(-po));
            const float e2c = __expf(2.f * cst);
            hval = o * ((e2c - 1.f) / (e2c + 1.f));

            hlog[(t & 63) * 256 + tid] = (_Float16)hval;

            if (t + 1 < S_) {
                union { _Float16 hf; unsigned short us; } cv; cv.hf = (_Float16)hval;
                const unsigned word = ((unsigned)(t + 1) << 16) | (unsigned)cv.us;
                unsigned* hp = hbuf + (size_t)((t + 1) % 3) * B_ * H_ + (size_t)gb * H_ + gh;
                asm volatile("global_store_dword %0, %1, off sc0 sc1"
                             :: "v"(hp), "v"(word) : "memory");
            }
        }

        // ---- pre-issue tags(t+1) + counted tail ----
        if (t + 1 < S_) {
            const unsigned* hn = hbuf + (size_t)((t + 1) % 3) * B_ * H_
                                      + (size_t)arow * H_ + w * 128 + kblk * 8;
            #pragma unroll
            for (int s = 0; s < 4; ++s) {
                asm volatile("global_load_dwordx4 %0, %1, off sc0 sc1"
                             : "=v"(q[2 * s]) : "v"(hn + s * 32));
                asm volatile("global_load_dwordx4 %0, %1, off sc0 sc1"
                             : "=v"(q[2 * s + 1]) : "v"(hn + s * 32 + 4));
            }
            if (ownerw) { asm volatile("s_waitcnt vmcnt(9)" ::: "memory"); }
            else        { asm volatile("s_waitcnt vmcnt(8)" ::: "memory"); }
            __builtin_amdgcn_sched_barrier(0);
            #pragma unroll
            for (int r2 = 0; r2 < 4; ++r2) { xf0[r2] = (_Float16)xn0[r2]; xf0[4 + r2] = (_Float16)xn1[r2]; }
            #pragma unroll
            for (int r2 = 0; r2 < 4; ++r2) { xf1[r2] = (_Float16)xn2[r2]; xf1[4 + r2] = (_Float16)xn3[r2]; }
            tv = tvn;
        }
    }

    // ---- final flush of last 32 steps + final states ----
    __syncthreads();
    {
        const int tbase = S_ - 32;
        #pragma unroll
        for (int p = 0; p < 2; ++p) {
            const int m  = p * 512 + tid;
            const int dt = m >> 5;
            const int c  = m & 31;
            f16x8 v = *(const f16x8*)(hlog + ((tbase + dt) & 63) * 256 + c * 8);
            float* op = out + ((size_t)(r0 + (c >> 2)) * S_ + tbase + dt) * H_
                            + c0 + (c & 3) * 8;
            f32x4 o0, o1;
            #pragma unroll
            for (int r2 = 0; r2 < 4; ++r2) { o0[r2] = (float)v[r2]; o1[r2] = (float)v[4 + r2]; }
            asm volatile("global_store_dwordx4 %0, %1, off" :: "v"(op), "v"(o0) : "memory");
            asm volatile("global_store_dwordx4 %0, %1, off" :: "v"(op + 4), "v"(o1) : "memory");
        }
    }
    if (tid < 256) {
        const size_t BSH = (size_t)B_ * S_ * H_;
        out[BSH +                       (size_t)gb * H_ + gh] = hval;  // h_T
        out[BSH + (size_t)B_ * H_ +     (size_t)gb * H_ + gh] = cst;   // c_T
        out[BSH + 2 * (size_t)B_ * H_ + (size_t)gb * H_ + gh] = kst;   // k_T
    }
    asm volatile("s_waitcnt vmcnt(0)" ::: "memory");   // commit asm stores
}

extern "C" void kernel_launch(void* const* d_in, const int* in_sizes, int n_in,
                              void* d_out, int out_size, void* d_ws, size_t ws_size,
                              hipStream_t stream) {
    (void)in_sizes; (void)n_in; (void)out_size; (void)ws_size;
    const float* x  = (const float*)d_in[0];
    const float* ts = (const float*)d_in[1];
    const float* Ur = (const float*)d_in[2];
    const float* Wr = (const float*)d_in[3];
    const float* br = (const float*)d_in[4];
    const float* Uc = (const float*)d_in[5];
    const float* Wc = (const float*)d_in[6];
    const float* bc = (const float*)d_in[7];
    const float* Uo = (const float*)d_in[8];
    const float* Wo = (const float*)d_in[9];
    const float* bo = (const float*)d_in[10];
    float* out = (float*)d_out;

    char* ws = (char*)d_ws;
    unsigned*  hbuf = (unsigned*)(ws + WS_HBUF_OFF);
    _Float16*  Wt   = (_Float16*)(ws + WS_WT_OFF);

    // zero ALL 3 tagged-h slots every launch (stale tags from prior replay
    // would false-positive the exact-match poll). Slot 0 = {tag 0, h=0} ✓.
    hipMemsetAsync(hbuf, 0, 3 * B_ * H_ * 4, stream);

    prep_weights<<<192, 256, 0, stream>>>(Wr, Wc, Wo, Ur, Uc, Uo, Wt);

    plstm_reg<<<NBLK, NTHR, 0, stream>>>(x, ts, br, bc, bo, Wt, hbuf, out);
}

// Round 11
// 3583.233 us; speedup vs baseline: 3.0434x; 1.0290x over previous
//
#include <hip/hip_runtime.h>
#include <hip/hip_fp16.h>
#include <cstdint>
#include <cstddef>

// Problem constants
#define B_   64
#define S_   512
#define F_   512
#define H_   1024
#define KTOT 1536
#define EPS_ 1e-3f
#define NBLK 256
#define NTHR 512

typedef _Float16 f16x8 __attribute__((ext_vector_type(8)));
typedef float    f32x4 __attribute__((ext_vector_type(4)));
typedef unsigned u32x4 __attribute__((ext_vector_type(4)));

// workspace layout (bytes)
#define WS_HBUF_OFF 0                 // tagged h: u32[3][64][1024] = 768 KB
#define WS_WT_OFF   (1024*1024)       // fp16 [3*1024][1536] = 9 MB

#define MFMA16(A,Bf,C) __builtin_amdgcn_mfma_f32_16x16x32_f16(A, Bf, C, 0, 0, 0)

// ---------------- weight prep: fp16, transposed, [3*H][KTOT] ----------------
// Wt[(g*H + j)][k] = (k < H) ? W_g[k][j] : U_g[k-H][j]
__global__ void prep_weights(const float* __restrict__ Wr, const float* __restrict__ Wc,
                             const float* __restrict__ Wo, const float* __restrict__ Ur,
                             const float* __restrict__ Uc, const float* __restrict__ Uo,
                             _Float16* __restrict__ Wt) {
    int b  = blockIdx.x;            // 0..191
    int g  = b >> 6;                // gate 0..2
    int j0 = (b & 63) << 4;         // 16 columns per block
    const float* W = (g == 0) ? Wr : (g == 1) ? Wc : Wo;
    const float* U = (g == 0) ? Ur : (g == 1) ? Uc : Uo;
    int jj = threadIdx.x & 15;
    int kk = threadIdx.x >> 4;      // 0..15
    for (int k0 = 0; k0 < KTOT; k0 += 16) {
        int k = k0 + kk;
        float v = (k < H_) ? W[(size_t)k * H_ + j0 + jj]
                           : U[(size_t)(k - H_) * H_ + j0 + jj];
        Wt[(size_t)(g * H_ + j0 + jj) * KTOT + k] = (_Float16)v;
    }
}

// ---------------- persistent tagged-h recurrence kernel ----------------
// R8-verified structure (full-resweep poll, wave-uniform control flow,
// "=v" loads legal because every active lane rewrites every chunk) with
// three measured regressions removed:
//   - NO s_sleep backoff (R8: sleeping waves detect late, sweeps desync)
//   - NO tail vmcnt waits (barrier #1's implicit vmcnt(0) drain already
//     retires the x/ts prefetch; poll re-drains with vmcnt(0) anyway)
//   - flush by NON-OWNER waves, barrier #2 kept UNCONDITIONAL (convergent —
//     the R9/R10 divergent-barrier UB is gone)
// Barrier #2 is required: a wave can pass poll(t+1) via OTHER blocks'
// publishes while its own block's owners still read red (real race).
__global__ __launch_bounds__(NTHR, 2)
void plstm_reg(const float* __restrict__ x,
               const float* __restrict__ ts,
               const float* __restrict__ br,
               const float* __restrict__ bc,
               const float* __restrict__ bo,
               const _Float16* __restrict__ Wt,
               unsigned* __restrict__ hbuf,     // [3][64][1024] u32 tagged
               float* __restrict__ out) {
    __shared__ float    red[8 * 768];       // [wave][gate][8*32] = 24 KB
    __shared__ _Float16 hlog[64 * 256];     // 64-deep h log      = 32 KB

    const int tid = threadIdx.x;
    const int bid = blockIdx.x;
    const int grp = bid >> 5;            // batch-row group 0..7
    const int cg  = bid & 31;            // h-col group 0..31
    const int r0  = grp << 3;            // 8 rows
    const int c0  = cg << 5;             // 32 cols

    const int lane = tid & 63;
    const int w    = tid >> 6;           // wave 0..7
    const int arow = r0 + (lane & 7);    // A rows (M=8; lanes 8-15 duplicate)
    const int kblk = lane >> 4;          // 0..3
    const int jcol = lane & 15;          // B-fragment column within 16-col tile
    const bool ownerw = (w < 4);         // waves 0-3 = owner threads (tid<256)

    // ---- ALL weights into registers (AGPR-resident on gfx950) ----
    f16x8 bfh[3][2][4], bfx[3][2][2];
    #pragma unroll
    for (int g3 = 0; g3 < 3; ++g3)
        #pragma unroll
        for (int ct = 0; ct < 2; ++ct) {
            const _Float16* base = Wt + (size_t)(g3 * H_ + c0 + ct * 16 + jcol) * KTOT;
            #pragma unroll
            for (int sub = 0; sub < 4; ++sub)
                bfh[g3][ct][sub] = *(const f16x8*)(base + w * 128 + sub * 32 + kblk * 8);
            #pragma unroll
            for (int sub = 0; sub < 2; ++sub)
                bfx[g3][ct][sub] = *(const f16x8*)(base + H_ + w * 64 + sub * 32 + kblk * 8);
        }

    const int erow = tid >> 5;           // owner mapping (tid<256): 8 rows x 32 cols
    const int ecol = tid & 31;
    const int gb   = r0 + (erow & 7);
    const int gh   = c0 + ecol;
    float biasr = 0.f, biasc = 0.f, biaso = 0.f;
    if (tid < 256) { biasr = br[gh]; biasc = bc[gh]; biaso = bo[gh]; }
    float cst = 0.f, kst = 0.f, hval = 0.f;

    // ---- drain compiler-issued loads so the priming ledger starts at 0 ----
    asm volatile("s_waitcnt vmcnt(0)" ::: "memory");
    __builtin_amdgcn_sched_barrier(0);

    // ---- priming: x(0), ts(0, owners), tags(0); vmcnt(8) leaves tags in flight ----
    // ledger: owners x4+ts1+tags8=13 -> vmcnt(8) retires 5 (x,ts);
    //         non-owners x4+tags8=12 -> vmcnt(8) retires 4 (x).
    f32x4 xn0, xn1, xn2, xn3; float tvn = 0.f;
    u32x4 q[8];
    {
        const float* xp = x + (size_t)arow * S_ * F_ + w * 64 + kblk * 8;
        asm volatile("global_load_dwordx4 %0, %1, off" : "=v"(xn0) : "v"(xp));
        asm volatile("global_load_dwordx4 %0, %1, off" : "=v"(xn1) : "v"(xp + 4));
        asm volatile("global_load_dwordx4 %0, %1, off" : "=v"(xn2) : "v"(xp + 32));
        asm volatile("global_load_dwordx4 %0, %1, off" : "=v"(xn3) : "v"(xp + 36));
        if (ownerw) {
            const float* tp = ts + (size_t)gb * S_;
            asm volatile("global_load_dword %0, %1, off" : "=v"(tvn) : "v"(tp));
        }
        const unsigned* hb = hbuf + (size_t)arow * H_ + w * 128 + kblk * 8;  // slot 0
        #pragma unroll
        for (int s = 0; s < 4; ++s) {
            asm volatile("global_load_dwordx4 %0, %1, off sc0 sc1"
                         : "=v"(q[2 * s]) : "v"(hb + s * 32));
            asm volatile("global_load_dwordx4 %0, %1, off sc0 sc1"
                         : "=v"(q[2 * s + 1]) : "v"(hb + s * 32 + 4));
        }
    }
    asm volatile("s_waitcnt vmcnt(8)" ::: "memory");
    __builtin_amdgcn_sched_barrier(0);
    f16x8 xf0, xf1;
    #pragma unroll
    for (int r = 0; r < 4; ++r) { xf0[r] = (_Float16)xn0[r]; xf0[4 + r] = (_Float16)xn1[r]; }
    #pragma unroll
    for (int r = 0; r < 4; ++r) { xf1[r] = (_Float16)xn2[r]; xf1[4 + r] = (_Float16)xn3[r]; }
    float tv = tvn;

    for (int t = 0; t < S_; ++t) {
        // ---- x-part MFMAs (pure reg) overlap the tag-load flight ----
        f32x4 acc[3][2] = {};
        #pragma unroll
        for (int g3 = 0; g3 < 3; ++g3)
            #pragma unroll
            for (int ct = 0; ct < 2; ++ct) {
                acc[g3][ct] = MFMA16(xf0, bfx[g3][ct][0], acc[g3][ct]);
                acc[g3][ct] = MFMA16(xf1, bfx[g3][ct][1], acc[g3][ct]);
            }

        // ---- poll: all 32 tag-words must equal t (flat spin, full resweep) ----
        const unsigned* hb = hbuf + (size_t)(t % 3) * B_ * H_
                                  + (size_t)arow * H_ + w * 128 + kblk * 8;
        const unsigned tt = ((unsigned)t << 16) | (unsigned)t;
        for (unsigned it = 0;;) {
            asm volatile("s_waitcnt vmcnt(0)" ::: "memory");
            __builtin_amdgcn_sched_barrier(0);
            unsigned bad = 0;
            #pragma unroll
            for (int i = 0; i < 8; ++i) {
                unsigned t0 = __builtin_amdgcn_perm(q[i][1], q[i][0], 0x07060302u);
                unsigned t1 = __builtin_amdgcn_perm(q[i][3], q[i][2], 0x07060302u);
                bad |= (t0 ^ tt) | (t1 ^ tt);
            }
            if (__all(bad == 0)) break;
            if (++it > (1u << 16)) break;              // pathology guard
            #pragma unroll
            for (int s = 0; s < 4; ++s) {
                asm volatile("global_load_dwordx4 %0, %1, off sc0 sc1"
                             : "=v"(q[2 * s]) : "v"(hb + s * 32));
                asm volatile("global_load_dwordx4 %0, %1, off sc0 sc1"
                             : "=v"(q[2 * s + 1]) : "v"(hb + s * 32 + 4));
            }
        }

        // ---- strip tags -> h fragments ----
        f16x8 hfr[4];
        #pragma unroll
        for (int s = 0; s < 4; ++s) {
            union { u32x4 u; f16x8 f; } cv;
            cv.u[0] = __builtin_amdgcn_perm(q[2 * s][1],     q[2 * s][0],     0x05040100u);
            cv.u[1] = __builtin_amdgcn_perm(q[2 * s][3],     q[2 * s][2],     0x05040100u);
            cv.u[2] = __builtin_amdgcn_perm(q[2 * s + 1][1], q[2 * s + 1][0], 0x05040100u);
            cv.u[3] = __builtin_amdgcn_perm(q[2 * s + 1][3], q[2 * s + 1][2], 0x05040100u);
            hfr[s] = cv.f;
        }

        // ---- prefetch x, ts for t+1 (retired by barrier #1's implicit drain) ----
        if (t + 1 < S_) {
            const float* xp = x + ((size_t)arow * S_ + (t + 1)) * F_ + w * 64 + kblk * 8;
            asm volatile("global_load_dwordx4 %0, %1, off" : "=v"(xn0) : "v"(xp));
            asm volatile("global_load_dwordx4 %0, %1, off" : "=v"(xn1) : "v"(xp + 4));
            asm volatile("global_load_dwordx4 %0, %1, off" : "=v"(xn2) : "v"(xp + 32));
            asm volatile("global_load_dwordx4 %0, %1, off" : "=v"(xn3) : "v"(xp + 36));
            if (ownerw) {
                const float* tp = ts + (size_t)gb * S_ + (t + 1);
                asm volatile("global_load_dword %0, %1, off" : "=v"(tvn) : "v"(tp));
            }
        }

        // ---- h-part MFMAs (pure reg) ----
        #pragma unroll
        for (int s = 0; s < 4; ++s)
            #pragma unroll
            for (int g3 = 0; g3 < 3; ++g3) {
                acc[g3][0] = MFMA16(hfr[s], bfh[g3][0][s], acc[g3][0]);
                acc[g3][1] = MFMA16(hfr[s], bfh[g3][1][s], acc[g3][1]);
            }

        // ---- cross-wave reduce: explicit per-wave slots ----
        if (lane < 32) {
            float* rw = red + w * 768;
            const int crow = (lane >> 4) << 2;
            const int ccol = lane & 15;
            #pragma unroll
            for (int i = 0; i < 4; ++i) {
                const int rr = (crow + i) * 32 + ccol;
                rw[rr]              = acc[0][0][i];  rw[rr + 16]         = acc[0][1][i];
                rw[256 + rr]        = acc[1][0][i];  rw[256 + rr + 16]   = acc[1][1][i];
                rw[512 + rr]        = acc[2][0][i];  rw[512 + rr + 16]   = acc[2][1][i];
            }
        }
        __syncthreads();   // barrier #1 (drains vmcnt -> xn/tvn retired)

        // ---- owners: sum partials ----
        float pr = biasr, pc = biasc, po = biaso;
        if (tid < 256) {
            #pragma unroll
            for (int ww = 0; ww < 8; ++ww) {
                pr += red[ww * 768 + tid];
                pc += red[ww * 768 + 256 + tid];
                po += red[ww * 768 + 512 + tid];
            }
        }
        __syncthreads();   // barrier #2 (UNCONDITIONAL): red free for next step

        if (tid < 256) {
            // ---- elementwise pLSTM update (f32) ----
            const float r = 1.f / (1.f + __expf(-pr));
            kst = r * tv + (1.f - r) * kst;
            const float e2 = __expf(2.f * pc);
            const float ctil = (e2 - 1.f) / (e2 + 1.f);
            const float d = tv - kst;
            const float f = __fsqrt_rn((d + EPS_) / (d + 1.f));  // ((d+1)/(d+eps))^-0.5
            cst = f * cst + (1.f - f) * ctil;
            const float o = 1.f / (1.f + __expf(-po));
            const float e2c = __expf(2.f * cst);
            hval = o * ((e2c - 1.f) / (e2c + 1.f));

            // publish FIRST (serial chain), then bookkeeping
            if (t + 1 < S_) {
                union { _Float16 hf; unsigned short us; } cv; cv.hf = (_Float16)hval;
                const unsigned word = ((unsigned)(t + 1) << 16) | (unsigned)cv.us;
                unsigned* hp = hbuf + (size_t)((t + 1) % 3) * B_ * H_ + (size_t)gb * H_ + gh;
                asm volatile("global_store_dword %0, %1, off sc0 sc1"
                             :: "v"(hp), "v"(word) : "memory");
            }
            hlog[(t & 63) * 256 + tid] = (_Float16)hval;
        } else if ((t & 31) == 0 && t) {
            // ---- non-owners: burst-flush hlog every 32 steps (off owner path) ----
            const int tbase = t - 32;
            #pragma unroll
            for (int p = 0; p < 4; ++p) {
                const int m  = p * 256 + (tid - 256);  // 0..1023 chunks of 8 fp16
                const int dt = m >> 5;                 // 0..31
                const int c  = m & 31;                 // chunk within step
                f16x8 v = *(const f16x8*)(hlog + ((tbase + dt) & 63) * 256 + c * 8);
                float* op = out + ((size_t)(r0 + (c >> 2)) * S_ + tbase + dt) * H_
                                + c0 + (c & 3) * 8;
                f32x4 o0, o1;
                #pragma unroll
                for (int r2 = 0; r2 < 4; ++r2) { o0[r2] = (float)v[r2]; o1[r2] = (float)v[4 + r2]; }
                asm volatile("global_store_dwordx4 %0, %1, off" :: "v"(op), "v"(o0) : "memory");
                asm volatile("global_store_dwordx4 %0, %1, off" :: "v"(op + 4), "v"(o1) : "memory");
            }
        }

        // ---- pre-issue tags(t+1); NO tail wait (barrier drains did the work) ----
        if (t + 1 < S_) {
            const unsigned* hn = hbuf + (size_t)((t + 1) % 3) * B_ * H_
                                      + (size_t)arow * H_ + w * 128 + kblk * 8;
            #pragma unroll
            for (int s = 0; s < 4; ++s) {
                asm volatile("global_load_dwordx4 %0, %1, off sc0 sc1"
                             : "=v"(q[2 * s]) : "v"(hn + s * 32));
                asm volatile("global_load_dwordx4 %0, %1, off sc0 sc1"
                             : "=v"(q[2 * s + 1]) : "v"(hn + s * 32 + 4));
            }
            #pragma unroll
            for (int r2 = 0; r2 < 4; ++r2) { xf0[r2] = (_Float16)xn0[r2]; xf0[4 + r2] = (_Float16)xn1[r2]; }
            #pragma unroll
            for (int r2 = 0; r2 < 4; ++r2) { xf1[r2] = (_Float16)xn2[r2]; xf1[4 + r2] = (_Float16)xn3[r2]; }
            tv = tvn;
        }
    }

    // ---- final flush of last 32 steps + final states ----
    __syncthreads();
    {
        const int tbase = S_ - 32;
        #pragma unroll
        for (int p = 0; p < 2; ++p) {
            const int m  = p * 512 + tid;
            const int dt = m >> 5;
            const int c  = m & 31;
            f16x8 v = *(const f16x8*)(hlog + ((tbase + dt) & 63) * 256 + c * 8);
            float* op = out + ((size_t)(r0 + (c >> 2)) * S_ + tbase + dt) * H_
                            + c0 + (c & 3) * 8;
            f32x4 o0, o1;
            #pragma unroll
            for (int r2 = 0; r2 < 4; ++r2) { o0[r2] = (float)v[r2]; o1[r2] = (float)v[4 + r2]; }
            asm volatile("global_store_dwordx4 %0, %1, off" :: "v"(op), "v"(o0) : "memory");
            asm volatile("global_store_dwordx4 %0, %1, off" :: "v"(op + 4), "v"(o1) : "memory");
        }
    }
    if (tid < 256) {
        const size_t BSH = (size_t)B_ * S_ * H_;
        out[BSH +                       (size_t)gb * H_ + gh] = hval;  // h_T
        out[BSH + (size_t)B_ * H_ +     (size_t)gb * H_ + gh] = cst;   // c_T
        out[BSH + 2 * (size_t)B_ * H_ + (size_t)gb * H_ + gh] = kst;   // k_T
    }
    asm volatile("s_waitcnt vmcnt(0)" ::: "memory");   // commit asm stores
}

extern "C" void kernel_launch(void* const* d_in, const int* in_sizes, int n_in,
                              void* d_out, int out_size, void* d_ws, size_t ws_size,
                              hipStream_t stream) {
    (void)in_sizes; (void)n_in; (void)out_size; (void)ws_size;
    const float* x  = (const float*)d_in[0];
    const float* ts = (const float*)d_in[1];
    const float* Ur = (const float*)d_in[2];
    const float* Wr = (const float*)d_in[3];
    const float* br = (const float*)d_in[4];
    const float* Uc = (const float*)d_in[5];
    const float* Wc = (const float*)d_in[6];
    const float* bc = (const float*)d_in[7];
    const float* Uo = (const float*)d_in[8];
    const float* Wo = (const float*)d_in[9];
    const float* bo = (const float*)d_in[10];
    float* out = (float*)d_out;

    char* ws = (char*)d_ws;
    unsigned*  hbuf = (unsigned*)(ws + WS_HBUF_OFF);
    _Float16*  Wt   = (_Float16*)(ws + WS_WT_OFF);

    // zero ALL 3 tagged-h slots every launch (stale tags from prior replay
    // would false-positive the exact-match poll). Slot 0 = {tag 0, h=0} ✓.
    hipMemsetAsync(hbuf, 0, 3 * B_ * H_ * 4, stream);

    prep_weights<<<192, 256, 0, stream>>>(Wr, Wc, Wo, Ur, Uc, Uo, Wt);

    plstm_reg<<<NBLK, NTHR, 0, stream>>>(x, ts, br, bc, bo, Wt, hbuf, out);
}

// Round 12
// 1812.381 us; speedup vs baseline: 6.0171x; 1.9771x over previous
//
#include <hip/hip_runtime.h>
#include <hip/hip_fp16.h>
#include <cstdint>
#include <cstddef>

// Problem constants
#define B_   64
#define S_   512
#define F_   512
#define H_   1024
#define KTOT 1536
#define EPS_ 1e-3f
#define NBLK 256
#define NTHR 512

typedef _Float16 f16x8 __attribute__((ext_vector_type(8)));
typedef float    f32x4 __attribute__((ext_vector_type(4)));

// workspace layout (bytes)
#define WS_CNT_OFF  0                 // u32 counter per group, 128B-padded: 8*128 = 1 KB
#define WS_HBUF_OFF 4096              // fp16 h: [3][64][1024] = 384 KB
#define WS_WT_OFF   (1024*1024)       // fp16 [3*1024][1536] = 9 MB

#define MFMA16(A,Bf,C) __builtin_amdgcn_mfma_f32_16x16x32_f16(A, Bf, C, 0, 0, 0)

// ---------------- weight prep: fp16, transposed, [3*H][KTOT] ----------------
// Wt[(g*H + j)][k] = (k < H) ? W_g[k][j] : U_g[k-H][j]
__global__ void prep_weights(const float* __restrict__ Wr, const float* __restrict__ Wc,
                             const float* __restrict__ Wo, const float* __restrict__ Ur,
                             const float* __restrict__ Uc, const float* __restrict__ Uo,
                             _Float16* __restrict__ Wt) {
    int b  = blockIdx.x;            // 0..191
    int g  = b >> 6;                // gate 0..2
    int j0 = (b & 63) << 4;         // 16 columns per block
    const float* W = (g == 0) ? Wr : (g == 1) ? Wc : Wo;
    const float* U = (g == 0) ? Ur : (g == 1) ? Uc : Uo;
    int jj = threadIdx.x & 15;
    int kk = threadIdx.x >> 4;      // 0..15
    for (int k0 = 0; k0 < KTOT; k0 += 16) {
        int k = k0 + kk;
        float v = (k < H_) ? W[(size_t)k * H_ + j0 + jj]
                           : U[(size_t)(k - H_) * H_ + j0 + jj];
        Wt[(size_t)(g * H_ + j0 + jj) * KTOT + k] = (_Float16)v;
    }
}

// ---------------- persistent counter-sync recurrence kernel ----------------
// 256 blocks x 512 threads (8 waves). group = bid>>5 (8 batch rows),
// cg = bid&31 (32 h-cols). Wave w K-split: h-k [128w,+128), x-k [64w,+64).
// Weights register-resident. SYNC REDESIGN (R11 post-mortem: tag-fused polls
// re-read 16 MB/sweep device-wide through the LLC — detection cost ≈ data
// cost × retries): detection now via ONE per-group arrival counter.
//   producer: h fp16 stores sc0sc1 -> vmcnt(0) (ACKed in LLC) -> barrier ->
//             tid0 atomicAdd(cnt[group], 1)   (32 blocks/group/step)
//   consumer: poll cnt[group] (single dword, all lanes same addr) until
//             >= 32*t, then load h data ONCE (sc0sc1, plain fp16, no tags).
// Counter is monotone -> no livelock, no cascade, no vmcnt ledgers (all
// waits are plain vmcnt(0)). Triple-buffered h (skew-safe with margin).
__global__ __launch_bounds__(NTHR, 2)
void plstm_cnt(const float* __restrict__ x,
               const float* __restrict__ ts,
               const float* __restrict__ br,
               const float* __restrict__ bc,
               const float* __restrict__ bo,
               const _Float16* __restrict__ Wt,
               _Float16* __restrict__ hbuf,     // [3][64][1024] fp16
               unsigned* __restrict__ cnt,      // [8] counters, 128B apart
               float* __restrict__ out) {
    __shared__ float    red[8 * 768];       // [wave][gate][8*32] = 24 KB
    __shared__ _Float16 hlog[64 * 256];     // 64-deep h log      = 32 KB

    const int tid = threadIdx.x;
    const int bid = blockIdx.x;
    const int grp = bid >> 5;            // batch-row group 0..7
    const int cg  = bid & 31;            // h-col group 0..31
    const int r0  = grp << 3;            // 8 rows
    const int c0  = cg << 5;             // 32 cols

    const int lane = tid & 63;
    const int w    = tid >> 6;           // wave 0..7
    const int arow = r0 + (lane & 7);    // A rows (M=8; lanes 8-15 duplicate)
    const int kblk = lane >> 4;          // 0..3
    const int jcol = lane & 15;          // B-fragment column within 16-col tile

    // ---- ALL weights into registers (AGPR-resident on gfx950) ----
    f16x8 bfh[3][2][4], bfx[3][2][2];
    #pragma unroll
    for (int g3 = 0; g3 < 3; ++g3)
        #pragma unroll
        for (int ct = 0; ct < 2; ++ct) {
            const _Float16* base = Wt + (size_t)(g3 * H_ + c0 + ct * 16 + jcol) * KTOT;
            #pragma unroll
            for (int sub = 0; sub < 4; ++sub)
                bfh[g3][ct][sub] = *(const f16x8*)(base + w * 128 + sub * 32 + kblk * 8);
            #pragma unroll
            for (int sub = 0; sub < 2; ++sub)
                bfx[g3][ct][sub] = *(const f16x8*)(base + H_ + w * 64 + sub * 32 + kblk * 8);
        }

    const int erow = tid >> 5;           // owner mapping (tid<256): 8 rows x 32 cols
    const int ecol = tid & 31;
    const int gb   = r0 + (erow & 7);
    const int gh   = c0 + ecol;
    float biasr = 0.f, biasc = 0.f, biaso = 0.f;
    if (tid < 256) { biasr = br[gh]; biasc = bc[gh]; biaso = bo[gh]; }
    float cst = 0.f, kst = 0.f, hval = 0.f;

    const unsigned* const cp = cnt + grp * 32;   // this group's counter (128B line)

    // ---- priming: x(0), ts(0) via plain loads (compiler-managed waits) ----
    f32x4 xn0, xn1, xn2, xn3; float tvn = 0.f;
    {
        const float* xp = x + (size_t)arow * S_ * F_ + w * 64 + kblk * 8;
        xn0 = *(const f32x4*)xp;        xn1 = *(const f32x4*)(xp + 4);
        xn2 = *(const f32x4*)(xp + 32); xn3 = *(const f32x4*)(xp + 36);
        if (tid < 256) tvn = ts[(size_t)gb * S_];
        else if (w < 4) tvn = 0.f;
    }
    f16x8 xf0, xf1;
    #pragma unroll
    for (int r = 0; r < 4; ++r) { xf0[r] = (_Float16)xn0[r]; xf0[4 + r] = (_Float16)xn1[r]; }
    #pragma unroll
    for (int r = 0; r < 4; ++r) { xf1[r] = (_Float16)xn2[r]; xf1[4 + r] = (_Float16)xn3[r]; }
    float tv = tvn;

    for (int t = 0; t < S_; ++t) {
        // ---- x-part MFMAs (pure reg) overlap the counter round trip ----
        f32x4 acc[3][2] = {};
        #pragma unroll
        for (int g3 = 0; g3 < 3; ++g3)
            #pragma unroll
            for (int ct = 0; ct < 2; ++ct) {
                acc[g3][ct] = MFMA16(xf0, bfx[g3][ct][0], acc[g3][ct]);
                acc[g3][ct] = MFMA16(xf1, bfx[g3][ct][1], acc[g3][ct]);
            }

        // ---- detect: poll ONE dword until all 32 group blocks arrived ----
        if (t > 0) {
            const unsigned tgt = 32u * (unsigned)t;
            unsigned c;
            for (unsigned it = 0; it < (1u << 17); ++it) {
                asm volatile("global_load_dword %0, %1, off sc0 sc1\n\t"
                             "s_waitcnt vmcnt(0)"
                             : "=v"(c) : "v"(cp) : "memory");
                if (c >= tgt) break;   // same addr across lanes -> uniform
            }
        }
        __builtin_amdgcn_sched_barrier(0);

        // ---- h data loads: ONCE, plain fp16, guaranteed fresh ----
        const _Float16* hb = hbuf + (size_t)(t % 3) * B_ * H_
                                  + (size_t)arow * H_ + w * 128 + kblk * 8;
        f16x8 hfr[4];
        #pragma unroll
        for (int s = 0; s < 4; ++s)
            asm volatile("global_load_dwordx4 %0, %1, off sc0 sc1"
                         : "=v"(hfr[s]) : "v"(hb + s * 32));
        asm volatile("s_waitcnt vmcnt(0)" ::: "memory");
        __builtin_amdgcn_sched_barrier(0);

        // ---- prefetch x, ts for t+1 (plain loads, hidden under h-MFMAs) ----
        if (t + 1 < S_) {
            const float* xp = x + ((size_t)arow * S_ + (t + 1)) * F_ + w * 64 + kblk * 8;
            xn0 = *(const f32x4*)xp;        xn1 = *(const f32x4*)(xp + 4);
            xn2 = *(const f32x4*)(xp + 32); xn3 = *(const f32x4*)(xp + 36);
            if (tid < 256) tvn = ts[(size_t)gb * S_ + t + 1];
        }

        // ---- h-part MFMAs (pure reg) ----
        #pragma unroll
        for (int s = 0; s < 4; ++s)
            #pragma unroll
            for (int g3 = 0; g3 < 3; ++g3) {
                acc[g3][0] = MFMA16(hfr[s], bfh[g3][0][s], acc[g3][0]);
                acc[g3][1] = MFMA16(hfr[s], bfh[g3][1][s], acc[g3][1]);
            }

        // ---- cross-wave reduce: explicit per-wave slots ----
        if (lane < 32) {
            float* rw = red + w * 768;
            const int crow = (lane >> 4) << 2;
            const int ccol = lane & 15;
            #pragma unroll
            for (int i = 0; i < 4; ++i) {
                const int rr = (crow + i) * 32 + ccol;
                rw[rr]              = acc[0][0][i];  rw[rr + 16]         = acc[0][1][i];
                rw[256 + rr]        = acc[1][0][i];  rw[256 + rr + 16]   = acc[1][1][i];
                rw[512 + rr]        = acc[2][0][i];  rw[512 + rr + 16]   = acc[2][1][i];
            }
        }
        __syncthreads();   // barrier #1: red ready

        // ---- owners: sum partials ----
        float pr = biasr, pc = biasc, po = biaso;
        if (tid < 256) {
            #pragma unroll
            for (int ww = 0; ww < 8; ++ww) {
                pr += red[ww * 768 + tid];
                pc += red[ww * 768 + 256 + tid];
                po += red[ww * 768 + 512 + tid];
            }
        }

        if (tid < 256) {
            // ---- elementwise pLSTM update (f32) ----
            const float r = 1.f / (1.f + __expf(-pr));
            kst = r * tv + (1.f - r) * kst;
            const float e2 = __expf(2.f * pc);
            const float ctil = (e2 - 1.f) / (e2 + 1.f);
            const float d = tv - kst;
            const float f = __fsqrt_rn((d + EPS_) / (d + 1.f));  // ((d+1)/(d+eps))^-0.5
            cst = f * cst + (1.f - f) * ctil;
            const float o = 1.f / (1.f + __expf(-po));
            const float e2c = __expf(2.f * cst);
            hval = o * ((e2c - 1.f) / (e2c + 1.f));

            // publish plain fp16 h for t+1 (sc0sc1 -> LLC)
            if (t + 1 < S_) {
                union { _Float16 hf; unsigned short us; } cv; cv.hf = (_Float16)hval;
                unsigned short* hp = (unsigned short*)(hbuf
                    + (size_t)((t + 1) % 3) * B_ * H_ + (size_t)gb * H_ + gh);
                unsigned uv = cv.us;
                asm volatile("global_store_short %0, %1, off sc0 sc1"
                             :: "v"(hp), "v"(uv) : "memory");
            }
            hlog[(t & 63) * 256 + tid] = (_Float16)hval;
        }

        // ---- ACK publishes, then arrive: one atomic per block ----
        asm volatile("s_waitcnt vmcnt(0)" ::: "memory");  // owner stores ACKed in LLC
        __syncthreads();   // barrier #2: all owner waves' publishes ACKed; red free
        if (tid == 0 && t + 1 < S_)
            __hip_atomic_fetch_add((unsigned*)cp, 1u,
                                   __ATOMIC_RELAXED, __HIP_MEMORY_SCOPE_AGENT);

        // ---- non-owners: burst-flush hlog every 32 steps (off critical path,
        //      overlapped with next step's x-MFMA + poll) ----
        if (tid >= 256 && (t & 31) == 0 && t) {
            const int tbase = t - 32;
            #pragma unroll
            for (int p = 0; p < 4; ++p) {
                const int m  = p * 256 + (tid - 256);  // 0..1023 chunks of 8 fp16
                const int dt = m >> 5;                 // 0..31
                const int c  = m & 31;                 // chunk within step
                f16x8 v = *(const f16x8*)(hlog + ((tbase + dt) & 63) * 256 + c * 8);
                float* op = out + ((size_t)(r0 + (c >> 2)) * S_ + tbase + dt) * H_
                                + c0 + (c & 3) * 8;
                f32x4 o0, o1;
                #pragma unroll
                for (int r2 = 0; r2 < 4; ++r2) { o0[r2] = (float)v[r2]; o1[r2] = (float)v[4 + r2]; }
                *(f32x4*)op = o0;
                *(f32x4*)(op + 4) = o1;
            }
        }

        // ---- tail: convert prefetched x ----
        if (t + 1 < S_) {
            #pragma unroll
            for (int r2 = 0; r2 < 4; ++r2) { xf0[r2] = (_Float16)xn0[r2]; xf0[4 + r2] = (_Float16)xn1[r2]; }
            #pragma unroll
            for (int r2 = 0; r2 < 4; ++r2) { xf1[r2] = (_Float16)xn2[r2]; xf1[4 + r2] = (_Float16)xn3[r2]; }
            tv = tvn;
        }
    }

    // ---- final flush of last 32 steps + final states ----
    __syncthreads();
    {
        const int tbase = S_ - 32;
        #pragma unroll
        for (int p = 0; p < 2; ++p) {
            const int m  = p * 512 + tid;
            const int dt = m >> 5;
            const int c  = m & 31;
            f16x8 v = *(const f16x8*)(hlog + ((tbase + dt) & 63) * 256 + c * 8);
            float* op = out + ((size_t)(r0 + (c >> 2)) * S_ + tbase + dt) * H_
                            + c0 + (c & 3) * 8;
            f32x4 o0, o1;
            #pragma unroll
            for (int r2 = 0; r2 < 4; ++r2) { o0[r2] = (float)v[r2]; o1[r2] = (float)v[4 + r2]; }
            *(f32x4*)op = o0;
            *(f32x4*)(op + 4) = o1;
        }
    }
    if (tid < 256) {
        const size_t BSH = (size_t)B_ * S_ * H_;
        out[BSH +                       (size_t)gb * H_ + gh] = hval;  // h_T
        out[BSH + (size_t)B_ * H_ +     (size_t)gb * H_ + gh] = cst;   // c_T
        out[BSH + 2 * (size_t)B_ * H_ + (size_t)gb * H_ + gh] = kst;   // k_T
    }
}

extern "C" void kernel_launch(void* const* d_in, const int* in_sizes, int n_in,
                              void* d_out, int out_size, void* d_ws, size_t ws_size,
                              hipStream_t stream) {
    (void)in_sizes; (void)n_in; (void)out_size; (void)ws_size;
    const float* x  = (const float*)d_in[0];
    const float* ts = (const float*)d_in[1];
    const float* Ur = (const float*)d_in[2];
    const float* Wr = (const float*)d_in[3];
    const float* br = (const float*)d_in[4];
    const float* Uc = (const float*)d_in[5];
    const float* Wc = (const float*)d_in[6];
    const float* bc = (const float*)d_in[7];
    const float* Uo = (const float*)d_in[8];
    const float* Wo = (const float*)d_in[9];
    const float* bo = (const float*)d_in[10];
    float* out = (float*)d_out;

    char* ws = (char*)d_ws;
    unsigned*  cnt  = (unsigned*)(ws + WS_CNT_OFF);
    _Float16*  hbuf = (_Float16*)(ws + WS_HBUF_OFF);
    _Float16*  Wt   = (_Float16*)(ws + WS_WT_OFF);

    // zero counters + ALL h slots every launch (monotone counters must restart
    // at 0 for graph replay; h slot 0 zero = valid h_0).
    hipMemsetAsync(ws, 0, WS_HBUF_OFF + 3 * B_ * H_ * 2, stream);

    prep_weights<<<192, 256, 0, stream>>>(Wr, Wc, Wo, Ur, Uc, Uo, Wt);

    plstm_cnt<<<NBLK, NTHR, 0, stream>>>(x, ts, br, bc, bo, Wt, hbuf, cnt, out);
}